// Round 4
// baseline (633.551 us; speedup 1.0000x reference)
//
#include <hip/hip_runtime.h>
#include <hip/hip_cooperative_groups.h>
#include <math.h>

namespace cg = cooperative_groups;

#define S 128
#define KA 25
#define PATCH 625
#define FEAT 1250
#define PI_F 3.14159265358979323846f
#define PADW 152             // 128 + 24; ALSO the x row stride (152x152 input)
#define PADA (PADW * PADW)   // 23104

#define NBLK 1024
#define NTHR 256
#define NWAVE 4096           // NBLK * 4
#define NPAIR 8192           // S*S / 2

// d_ws layout (floats):
//   [0, 23104)          padded lat0, 152x152, border 0
//   [23168, 46272)      padded latf, 152x152, border HOMEO_TARGET
//   [46336, 47360)      per-block corr partials (1024)
#define WS_LAT0P 0
#define WS_LATFP 23168
#define WS_PART 46336

#define NTILE 20480000
#define NF4T 5119999         // (NTILE - 3) / 4

// floor(r/25) for r in [0,625): r*10486>>18 (exact; 25*10486 = 2^18+6).
__device__ __forceinline__ int div25(int r) { return (r * 10486) >> 18; }
// window offset for patch index r: ki*152 + kj = r + 127*(r/25)
__device__ __forceinline__ int woff(int r) { return r + 127 * div25(r); }
// residue-split env slot: conflict-free when lanes walk r at stride 4
__device__ __forceinline__ int eslot(int r) { return (r & 3) * 160 + (r >> 2); }

// ---------------------------------------------------------------------------
// ONE cooperative kernel.  Previous 6-kernel pipeline was invariant at
// ~230 us across radically different per-kernel structures (never VALU-,
// BW-, or occupancy-bound) -> time lives at the 6 dispatch boundaries
// (launch + post-poison cold ramp + drain per kernel).  grid.sync() keeps
// the machine hot across the 3 true data dependencies.
// 1024 blocks x 256 thr, __launch_bounds__(256,4): <=128 VGPR -> 4 blocks/CU
// guaranteed co-resident (cooperative requirement).
// ---------------------------------------------------------------------------
__global__ __launch_bounds__(NTHR, 4) void k_all(const float* __restrict__ x,
                                                 const float* __restrict__ rfs,
                                                 const float* __restrict__ lw,
                                                 const float* __restrict__ ada,
                                                 float* __restrict__ raw_aff,
                                                 float* __restrict__ latf,
                                                 float* __restrict__ corr,
                                                 float* __restrict__ tiles,
                                                 float* __restrict__ ws) {
    cg::grid_group grid = cg::this_grid();
    __shared__ float s_ae[640];
    __shared__ float s_le[640];
    __shared__ float s_red[4];

    const int tid = threadIdx.x;
    const int lane = tid & 63;
    const int wv = tid >> 6;
    const int bid = blockIdx.x;
    const int gid = bid * NTHR + tid;
    const int wid = bid * 4 + wv;

    // ---- P0: env tables in LDS (per block, closed form, bit-identical to
    // the original) + border-only fill of the padded ws arrays -------------
    float m = 0.0f;
    for (int r = tid; r < PATCH; r += NTHR) {
        int qi = div25(r);
        float di = (float)qi - 12.0f;
        float dj = (float)(r - 25 * qi) - 12.0f;
        float d = sqrtf(di * di + dj * dj);
        float ae = 0.0f, le = 0.0f;
        if (d < 12.5f) {
            float c1 = cosf(d * (PI_F / 25.0f));
            ae = c1 * c1;
            float inh = 0.0f;
            if (d < 4.5f) {
                float c2 = cosf(d * (PI_F / 9.0f));
                inh = c2 * c2;
            }
            le = c1 * c1 * (1.0f - inh);
        }
        s_ae[eslot(r)] = ae;
        s_le[eslot(r)] = le;
        m = fmaxf(m, le);
    }
    if (tid < 12) {  // unused residue-split slots (q*160 + 157..159)
        int q = tid / 3, t = 157 + tid - 3 * q;
        s_ae[q * 160 + t] = 0.0f;
        s_le[q * 160 + t] = 0.0f;
    }
    for (int o = 32; o; o >>= 1) m = fmaxf(m, __shfl_down(m, o));
    if (!lane) s_red[wv] = m;
    __syncthreads();
    {
        float inv = 1.0f / fmaxf(fmaxf(s_red[0], s_red[1]),
                                 fmaxf(s_red[2], s_red[3]));
        for (int s = tid; s < 640; s += NTHR) s_le[s] *= inv;
    }
    // border ring only: interiors are written by P1/P2, so no cross-block race
    for (int i = gid; i < PADA; i += NBLK * NTHR) {
        int pi = i / PADW, pj = i - pi * PADW;
        if (pi < 12 || pi >= 140 || pj < 12 || pj >= 140) {
            ws[WS_LAT0P + i] = 0.0f;
            ws[WS_LATFP + i] = 0.04f;
        }
    }
    __syncthreads();

    // ---- P1: raw_aff + padded lat0, one wave per ROW-PAIR ----------------
    // pair p = rows (2p, 2p+1); rfs pair base = 2p*1250, always 16B-aligned
    // -> 625 aligned float4, ~10 independent loads/lane (max MLP), no peel.
    for (int p = wid; p < NPAIR; p += NWAVE) {
        const int l0 = 2 * p;
        const int li = l0 >> 7, lj = l0 & 127;   // lj even -> same row for l0+1
        const int wb = li * PADW + lj;
        const long B = (long)l0 * FEAT;
        float aA = 0.0f, aB = 0.0f;
        for (int k = lane; k < 625; k += 64) {
            const float4 rv = *reinterpret_cast<const float4*>(rfs + B + 4 * (long)k);
#pragma unroll
            for (int j = 0; j < 4; ++j) {
                int f = 4 * k + j;                 // [0, 2500)
                int row1 = (f >= FEAT) ? 1 : 0;
                int g = f - row1 * FEAT;
                int c = (g >= PATCH) ? 1 : 0;
                int r = g - c * PATCH;
                float t = x[c * PADA + wb + row1 + woff(r)] * s_ae[eslot(r)];
                float v = t * fmaxf((&rv.x)[j], 0.0f);
                aA += row1 ? 0.0f : v;
                aB += row1 ? v : 0.0f;
            }
        }
        for (int o = 32; o; o >>= 1) {
            aA += __shfl_down(aA, o);
            aB += __shfl_down(aB, o);
        }
        if (!lane) {
            raw_aff[l0]     = aA;
            raw_aff[l0 + 1] = aB;
            int pc = (li + 12) * PADW + (lj + 12);
            ws[WS_LAT0P + pc]     = fmaxf(aA - ada[l0],     0.0f);
            ws[WS_LAT0P + pc + 1] = fmaxf(aB - ada[l0 + 1], 0.0f);
        }
    }

    // ---- P1b: tiles writer (flat, aligned float4: element i aligned iff
    // i==3 mod 4 since tiles = out+32769).  x/env re-read is L1/LDS-hot. ----
    for (long k = gid; k < NF4T; k += (long)NBLK * NTHR) {
        long i0 = 3 + (k << 2);
        float4 v;
#pragma unroll
        for (int j = 0; j < 4; ++j) {
            unsigned int e = (unsigned int)(i0 + j);
            unsigned int l = e / 1250u;
            int f = (int)(e - l * 1250u);
            int c = (f >= PATCH) ? 1 : 0;
            int r = f - c * PATCH;
            int li2 = (int)(l >> 7), lj2 = (int)(l & 127u);
            (&v.x)[j] = x[c * PADA + li2 * PADW + lj2 + woff(r)] * s_ae[eslot(r)];
        }
        *reinterpret_cast<float4*>(tiles + i0) = v;
    }
    if (gid < 4) {                                // head 0,1,2 + tail
        unsigned int e = (gid < 3) ? (unsigned int)gid : (NTILE - 1u);
        unsigned int l = e / 1250u;
        int f = (int)(e - l * 1250u);
        int c = (f >= PATCH) ? 1 : 0;
        int r = f - c * PATCH;
        int li2 = (int)(l >> 7), lj2 = (int)(l & 127u);
        tiles[e] = x[c * PADA + li2 * PADW + lj2 + woff(r)] * s_ae[eslot(r)];
    }

    grid.sync();   // lat0 complete

    // ---- P2: final lat, pair-structured.  lw pair base = 1250p:
    // peel 2 iff p odd, then 312 aligned float4 (+2 tail iff p even). -------
    auto lat_pair = [&](int p) -> float2 {
        const int l0 = 2 * p;
        const int li = l0 >> 7, lj = l0 & 127;
        const int wb = li * PADW + lj;
        const long B = (long)p * FEAT;
        const int peel = (p & 1) ? 2 : 0;
        const float* __restrict__ plat0 = ws + WS_LAT0P;
        float aA = 0.0f, aB = 0.0f;
        if (lane < peel) {                        // f in {0,1}: row0, woff=f
            int f = lane;
            aA += plat0[wb + f] * s_le[eslot(f)] * fmaxf(lw[B + f], 0.0f);
        }
        for (int k = lane; k < 312; k += 64) {
            int f0 = peel + 4 * k;
            const float4 w4 = *reinterpret_cast<const float4*>(lw + B + f0);
#pragma unroll
            for (int j = 0; j < 4; ++j) {
                int f = f0 + j;                    // [0, 1250)
                int row1 = (f >= PATCH) ? 1 : 0;
                int r = f - row1 * PATCH;
                float gv = plat0[wb + row1 + woff(r)];
                float v = gv * s_le[eslot(r)] * fmaxf((&w4.x)[j], 0.0f);
                aA += row1 ? 0.0f : v;
                aB += row1 ? v : 0.0f;
            }
        }
        if (peel == 0 && lane < 2) {              // tail f = 1248,1249 (row1)
            int f = 1248 + lane;
            int r = f - PATCH;
            aB += plat0[wb + 1 + woff(r)] * s_le[eslot(r)] * fmaxf(lw[B + f], 0.0f);
        }
        for (int o = 32; o; o >>= 1) {
            aA += __shfl_down(aA, o);
            aB += __shfl_down(aB, o);
        }
        float2 lv = {0.0f, 0.0f};
        if (!lane) {
            float af0 = raw_aff[l0] - ada[l0];
            float L0 = tanhf(fmaxf(fmaxf(af0, 0.0f) - aA + af0, 0.0f));
            float af1 = raw_aff[l0 + 1] - ada[l0 + 1];
            float L1 = tanhf(fmaxf(fmaxf(af1, 0.0f) - aB + af1, 0.0f));
            latf[l0]     = L0;
            latf[l0 + 1] = L1;
            int pc = (li + 12) * PADW + (lj + 12);
            ws[WS_LATFP + pc]     = L0;
            ws[WS_LATFP + pc + 1] = L1;
            lv.x = L0; lv.y = L1;
        }
        return lv;   // lane0-valid; cached in regs for P3 (no reload)
    };
    const float2 lvA = lat_pair(wid);
    const float2 lvB = lat_pair(wid + NWAVE);

    grid.sync();   // latf complete

    // ---- P3: corr partials, same pair structure on padded latf -----------
    auto corr_pair = [&](int p) -> float2 {
        const int l0 = 2 * p;
        const int li = l0 >> 7, lj = l0 & 127;
        const int wb = li * PADW + lj;
        const long B = (long)p * FEAT;
        const int peel = (p & 1) ? 2 : 0;
        const float* __restrict__ platf = ws + WS_LATFP;
        float aA = 0.0f, aB = 0.0f;
        if (lane < peel) {
            int f = lane;
            aA += platf[wb + f] * s_le[eslot(f)] * fmaxf(lw[B + f], 0.0f);
        }
        for (int k = lane; k < 312; k += 64) {
            int f0 = peel + 4 * k;
            const float4 w4 = *reinterpret_cast<const float4*>(lw + B + f0);
#pragma unroll
            for (int j = 0; j < 4; ++j) {
                int f = f0 + j;
                int row1 = (f >= PATCH) ? 1 : 0;
                int r = f - row1 * PATCH;
                float gv = platf[wb + row1 + woff(r)];
                float v = gv * s_le[eslot(r)] * fmaxf((&w4.x)[j], 0.0f);
                aA += row1 ? 0.0f : v;
                aB += row1 ? v : 0.0f;
            }
        }
        if (peel == 0 && lane < 2) {
            int f = 1248 + lane;
            int r = f - PATCH;
            aB += platf[wb + 1 + woff(r)] * s_le[eslot(r)] * fmaxf(lw[B + f], 0.0f);
        }
        for (int o = 32; o; o >>= 1) {
            aA += __shfl_down(aA, o);
            aB += __shfl_down(aB, o);
        }
        return {aA, aB};
    };
    const float2 cA = corr_pair(wid);
    const float2 cB = corr_pair(wid + NWAVE);

    float wsum = 0.0f;
    if (!lane)
        wsum = cA.x * lvA.x + cA.y * lvA.y + cB.x * lvB.x + cB.y * lvB.y;
    if (!lane) s_red[wv] = wsum;
    __syncthreads();
    if (!tid)
        ws[WS_PART + bid] = s_red[0] + s_red[1] + s_red[2] + s_red[3];

    grid.sync();   // partials complete

    // ---- P4: deterministic reduce of 1024 partials (block 0) -------------
    if (bid == 0) {
        float a = 0.0f;
        for (int i = tid; i < NBLK; i += NTHR) a += ws[WS_PART + i];
        for (int o = 32; o; o >>= 1) a += __shfl_down(a, o);
        if (!lane) s_red[wv] = a;
        __syncthreads();
        if (!tid) corr[0] = s_red[0] + s_red[1] + s_red[2] + s_red[3];
    }
}

// ---------------------------------------------------------------------------
// d_out layout (flat, return order):
//   [0, 16384)              raw_aff   [1,1,128,128]
//   [16384, 32768)          lat       [1,1,128,128]
//   [32768]                 lat_correlations (scalar)
//   [32769, 32769+20480000) tiles     [16384, 1, 1250]
// ---------------------------------------------------------------------------
extern "C" void kernel_launch(void* const* d_in, const int* in_sizes, int n_in,
                              void* d_out, int out_size, void* d_ws, size_t ws_size,
                              hipStream_t stream) {
    const float* x   = (const float*)d_in[0];   // [1,2,152,152]
    const float* rfs = (const float*)d_in[1];   // [16384,1250,1]
    const float* lw  = (const float*)d_in[2];   // [16384,625,1]
    const float* ada = (const float*)d_in[3];   // [1,1,128,128]

    float* out      = (float*)d_out;
    float* raw_aff  = out;
    float* latf     = out + S * S;
    float* corr     = out + 2 * S * S;
    float* tiles    = out + 2 * S * S + 1;
    float* ws       = (float*)d_ws;

    void* args[] = {(void*)&x, (void*)&rfs, (void*)&lw, (void*)&ada,
                    (void*)&raw_aff, (void*)&latf, (void*)&corr,
                    (void*)&tiles, (void*)&ws};
    hipLaunchCooperativeKernel((const void*)k_all, dim3(NBLK), dim3(NTHR),
                               args, 0, stream);
}

// Round 5
// 227.286 us; speedup vs baseline: 2.7875x; 2.7875x over previous
//
#include <hip/hip_runtime.h>
#include <math.h>

#define S 128
#define KA 25
#define PATCH 625
#define FEAT 1250
#define PI_F 3.14159265358979323846f
#define PADW 152             // 128 + 24; ALSO the x row stride (152x152 input)
#define PADA (PADW * PADW)   // 23104

// Env tables residue-split: slot(r) = (r&3)*160 + (r>>2); in the f4 loops all
// lanes of a j-step share (r&3) -> stride-1 conflict-free LDS reads.
//
// d_ws layout (floats):
//   [0, 640)             LRI env (residue-split, normalized)
//   [640, 1280)          AFF env (residue-split)
//   [1280, 24384)        padded lat0, 152x152, border 0
//   [24384, 47488)       padded latf, 152x152, border HOMEO_TARGET
//   [47488, 51584)       per-block corr partials (4096)
#define WS_LRI 0
#define WS_AE 640
#define WS_LAT0P 1280
#define WS_LATFP 24384
#define WS_PART 47488
#define NPART 4096

// floor(r/25) for r in [0,625): exact (25*10486 = 2^18+6).
__device__ __forceinline__ int div25(int r) { return (r * 10486) >> 18; }
// window offset for patch index r: ki*152 + kj = r + 127*(r/25)
__device__ __forceinline__ int woff(int r) { return r + 127 * div25(r); }
__device__ __forceinline__ int eslot(int r) { return (r & 3) * 160 + (r >> 2); }

// ---------------------------------------------------------------------------
// Kernel 0 (16 blocks): block 0 builds env tables (bit-identical values to
// the original); all blocks fill the padded lat0 (0) / latf (0.04) arrays.
// ---------------------------------------------------------------------------
__global__ __launch_bounds__(256) void k_init(float* __restrict__ ws) {
    const int tid = threadIdx.x;
    if (blockIdx.x == 0) {
        __shared__ float s_tmp[640];
        __shared__ float s_red[4];
        for (int s = tid; s < 640; s += 256) {     // AFF env
            int q = s / 160, t = s - q * 160;
            int r = (t << 2) | q;
            float v = 0.0f;
            if (r < PATCH) {
                float di = (float)div25(r) - 12.0f;
                float dj = (float)(r - 25 * div25(r)) - 12.0f;
                float d = sqrtf(di * di + dj * dj);
                if (d < 12.5f) {
                    float c = cosf(d * (PI_F / 25.0f));
                    v = c * c;
                }
            }
            ws[WS_AE + s] = v;
        }
        float m = 0.0f;
        for (int s = tid; s < 640; s += 256) {     // LRI env
            int q = s / 160, t = s - q * 160;
            int r = (t << 2) | q;
            float v = 0.0f;
            if (r < PATCH) {
                float di = (float)div25(r) - 12.0f;
                float dj = (float)(r - 25 * div25(r)) - 12.0f;
                float d = sqrtf(di * di + dj * dj);
                if (d < 12.5f) {
                    float c1 = cosf(d * (PI_F / 25.0f));
                    float inh = 0.0f;
                    if (d < 4.5f) {
                        float c2 = cosf(d * (PI_F / 9.0f));
                        inh = c2 * c2;
                    }
                    v = c1 * c1 * (1.0f - inh);
                }
            }
            s_tmp[s] = v;
            m = fmaxf(m, v);
        }
        for (int o = 32; o; o >>= 1) m = fmaxf(m, __shfl_down(m, o));
        if (!(tid & 63)) s_red[tid >> 6] = m;
        __syncthreads();
        float inv = 1.0f / fmaxf(fmaxf(s_red[0], s_red[1]),
                                 fmaxf(s_red[2], s_red[3]));
        for (int s = tid; s < 640; s += 256) ws[WS_LRI + s] = s_tmp[s] * inv;
    }
    const int gid = blockIdx.x * 256 + tid;
    const int gsz = gridDim.x * 256;
    for (int i = gid; i < 2 * PADA; i += gsz) {
        if (i < PADA) ws[WS_LAT0P + i] = 0.0f;
        else          ws[WS_LATFP + i - PADA] = 0.04f;
    }
}

// ---------------------------------------------------------------------------
// Kernel 1: FUSED tiles + raw_aff + padded lat0.  One wave per row l (4096
// blocks x 4 waves).  The x-gathers are computed ONCE and feed both the
// tiles store and the dot with relu(rfs).
// MLP fix (this round's lever): the rfs row is read as 4 uniform-trip
// prefetched float4 + 1 predicated (312 = 4*64 + 56), ALL issued before any
// consume -> 4-5 outstanding HBM loads per lane instead of the 1 the
// compiler produced at 16-32 VGPRs (the latency wall of rounds 0-4).
// ---------------------------------------------------------------------------
__global__ __launch_bounds__(256) void k_afftiles(const float* __restrict__ x,
                                                  const float* __restrict__ rfs,
                                                  const float* __restrict__ ada,
                                                  float* __restrict__ raw_aff,
                                                  float* __restrict__ tiles,
                                                  float* __restrict__ ws) {
    __shared__ float s_ae[640];
    const int tid = threadIdx.x;
    for (int i = tid; i < 640; i += 256) s_ae[i] = ws[WS_AE + i];
    __syncthreads();

    const int lane = tid & 63;
    const int l = blockIdx.x * 4 + (tid >> 6);     // 16384 waves, 1 row each
    const int li = l >> 7, lj = l & 127;
    const int wb = li * PADW + lj;                 // x row stride is also 152
    const long B = (long)l * FEAT;
    const int peel = (l & 1) ? 2 : 0;              // (1250*l) mod 4 = 2*(l&1)

    float acc = 0.0f;
    if (lane < peel) {                              // f in {0,1}: c=0, woff=f
        int f = lane;
        float t = x[wb + f] * s_ae[eslot(f)];
        tiles[B + f] = t;
        acc += t * fmaxf(rfs[B + f], 0.0f);
    }

    // ---- prefetch: 312 aligned float4 at rfs + B + peel ----
    const float* __restrict__ rb = rfs + B + peel;
    const float4 rv0 = *reinterpret_cast<const float4*>(rb + 4 * lane);
    const float4 rv1 = *reinterpret_cast<const float4*>(rb + 4 * (lane + 64));
    const float4 rv2 = *reinterpret_cast<const float4*>(rb + 4 * (lane + 128));
    const float4 rv3 = *reinterpret_cast<const float4*>(rb + 4 * (lane + 192));
    float4 rv4 = {0.0f, 0.0f, 0.0f, 0.0f};
    if (lane < 56) rv4 = *reinterpret_cast<const float4*>(rb + 4 * (lane + 256));

    auto consume = [&](const float4& rv, int k) {
        const int f0 = peel + 4 * k;
#pragma unroll
        for (int j = 0; j < 4; ++j) {
            int f = f0 + j;
            int c = (f >= PATCH) ? 1 : 0;
            int r = f - c * PATCH;
            float t = x[c * PADA + wb + woff(r)] * s_ae[eslot(r)];
            tiles[B + f] = t;
            acc += t * fmaxf((&rv.x)[j], 0.0f);
        }
    };
    consume(rv0, lane);
    consume(rv1, lane + 64);
    consume(rv2, lane + 128);
    consume(rv3, lane + 192);
    if (lane < 56) consume(rv4, lane + 256);

    if (lane < 2 - peel) {                          // l even: f = 1248,1249 (c=1)
        int f = 1248 + lane;
        int r = f - PATCH;
        float t = x[PADA + wb + woff(r)] * s_ae[eslot(r)];
        tiles[B + f] = t;
        acc += t * fmaxf(rfs[B + f], 0.0f);
    }

    for (int o = 32; o; o >>= 1) acc += __shfl_down(acc, o);
    if (!lane) {
        raw_aff[l] = acc;
        ws[WS_LAT0P + (li + 12) * PADW + (lj + 12)] = fmaxf(acc - ada[l], 0.0f);
    }
}

// ---------------------------------------------------------------------------
// Kernel 2: final lat.  One wave per row (4096 blocks).  lw row read as
// 2 uniform + 1 predicated prefetched float4 (n4 = 155/156 = 2*64 + rem).
// lat0 gathered from the padded array (L2-hot, 90 KB).
// ---------------------------------------------------------------------------
__global__ __launch_bounds__(256) void k_lat(const float* __restrict__ raw_aff,
                                             const float* __restrict__ ada,
                                             const float* __restrict__ lw,
                                             float* __restrict__ latf,
                                             float* __restrict__ ws) {
    __shared__ float s_le[640];
    const int tid = threadIdx.x;
    for (int i = tid; i < 640; i += 256) s_le[i] = ws[WS_LRI + i];
    __syncthreads();

    const int lane = tid & 63;
    const int l = blockIdx.x * 4 + (tid >> 6);
    const int li = l >> 7, lj = l & 127;
    const int wb = li * PADW + lj;
    const long B = (long)l * PATCH;
    const int peel = (4 - (l & 3)) & 3;            // (625*l) mod 4 = l mod 4
    const int n4 = (PATCH - peel) >> 2;            // 155 or 156
    const int tail = (PATCH - peel) & 3;
    const float* __restrict__ plat0 = ws + WS_LAT0P;

    float acc = 0.0f;
    if (lane < peel) {                              // f<3: woff(f)=f
        int f = lane;
        acc += plat0[wb + f] * s_le[eslot(f)] * fmaxf(lw[B + f], 0.0f);
    }
    const float* __restrict__ wbp = lw + B + peel;
    const float4 w0 = *reinterpret_cast<const float4*>(wbp + 4 * lane);
    const float4 w1 = *reinterpret_cast<const float4*>(wbp + 4 * (lane + 64));
    const int rem = n4 - 128;                      // 27 or 28
    float4 w2 = {0.0f, 0.0f, 0.0f, 0.0f};
    if (lane < rem) w2 = *reinterpret_cast<const float4*>(wbp + 4 * (lane + 128));

    auto consume = [&](const float4& w, int k) {
        const int f0 = peel + 4 * k;
#pragma unroll
        for (int j = 0; j < 4; ++j) {
            int f = f0 + j;
            acc += plat0[wb + woff(f)] * s_le[eslot(f)] * fmaxf((&w.x)[j], 0.0f);
        }
    };
    consume(w0, lane);
    consume(w1, lane + 64);
    if (lane < rem) consume(w2, lane + 128);
    if (lane < tail) {
        int f = peel + 4 * n4 + lane;
        acc += plat0[wb + woff(f)] * s_le[eslot(f)] * fmaxf(lw[B + f], 0.0f);
    }
    for (int o = 32; o; o >>= 1) acc += __shfl_down(acc, o);

    if (!lane) {
        float aff_l = raw_aff[l] - ada[l];
        float lat0_l = fmaxf(aff_l, 0.0f);
        float v = (lat0_l - acc) /* *STRENGTH=1 */ + aff_l;
        float lv = tanhf(fmaxf(v, 0.0f));
        latf[l] = lv;
        ws[WS_LATFP + (li + 12) * PADW + (lj + 12)] = lv;
    }
}

// ---------------------------------------------------------------------------
// Kernel 3: corr partials.  Same structure on padded latf (border 0.04).
// ---------------------------------------------------------------------------
__global__ __launch_bounds__(256) void k_corr(const float* __restrict__ latf,
                                              const float* __restrict__ lw,
                                              float* __restrict__ ws) {
    __shared__ float s_le[640];
    __shared__ float s_red[4];
    const int tid = threadIdx.x;
    for (int i = tid; i < 640; i += 256) s_le[i] = ws[WS_LRI + i];
    __syncthreads();

    const int lane = tid & 63, wv = tid >> 6;
    const int l = blockIdx.x * 4 + wv;
    const int li = l >> 7, lj = l & 127;
    const int wb = li * PADW + lj;
    const long B = (long)l * PATCH;
    const int peel = (4 - (l & 3)) & 3;
    const int n4 = (PATCH - peel) >> 2;
    const int tail = (PATCH - peel) & 3;
    const float* __restrict__ platf = ws + WS_LATFP;

    float acc = 0.0f;
    if (lane < peel) {
        int f = lane;
        acc += platf[wb + f] * s_le[eslot(f)] * fmaxf(lw[B + f], 0.0f);
    }
    const float* __restrict__ wbp = lw + B + peel;
    const float4 w0 = *reinterpret_cast<const float4*>(wbp + 4 * lane);
    const float4 w1 = *reinterpret_cast<const float4*>(wbp + 4 * (lane + 64));
    const int rem = n4 - 128;
    float4 w2 = {0.0f, 0.0f, 0.0f, 0.0f};
    if (lane < rem) w2 = *reinterpret_cast<const float4*>(wbp + 4 * (lane + 128));

    auto consume = [&](const float4& w, int k) {
        const int f0 = peel + 4 * k;
#pragma unroll
        for (int j = 0; j < 4; ++j) {
            int f = f0 + j;
            acc += platf[wb + woff(f)] * s_le[eslot(f)] * fmaxf((&w.x)[j], 0.0f);
        }
    };
    consume(w0, lane);
    consume(w1, lane + 64);
    if (lane < rem) consume(w2, lane + 128);
    if (lane < tail) {
        int f = peel + 4 * n4 + lane;
        acc += platf[wb + woff(f)] * s_le[eslot(f)] * fmaxf(lw[B + f], 0.0f);
    }
    for (int o = 32; o; o >>= 1) acc += __shfl_down(acc, o);

    if (!lane) s_red[wv] = acc * latf[l];
    __syncthreads();
    if (!tid)
        ws[WS_PART + blockIdx.x] = s_red[0] + s_red[1] + s_red[2] + s_red[3];
}

// ---------------------------------------------------------------------------
// Kernel 4: deterministic sum of 4096 partials -> corr scalar.
// ---------------------------------------------------------------------------
__global__ __launch_bounds__(256) void k_reduce(const float* __restrict__ ws,
                                                float* __restrict__ corr) {
    __shared__ float s_red[4];
    const int tid = threadIdx.x;
    const int lane = tid & 63, wv = tid >> 6;
    float acc = 0.0f;
    for (int i = tid; i < NPART; i += 256) acc += ws[WS_PART + i];
    for (int o = 32; o; o >>= 1) acc += __shfl_down(acc, o);
    if (!lane) s_red[wv] = acc;
    __syncthreads();
    if (!tid) corr[0] = s_red[0] + s_red[1] + s_red[2] + s_red[3];
}

// ---------------------------------------------------------------------------
// d_out layout (flat, return order):
//   [0, 16384)              raw_aff   [1,1,128,128]
//   [16384, 32768)          lat       [1,1,128,128]
//   [32768]                 lat_correlations (scalar)
//   [32769, 32769+20480000) tiles     [16384, 1, 1250]
// ---------------------------------------------------------------------------
extern "C" void kernel_launch(void* const* d_in, const int* in_sizes, int n_in,
                              void* d_out, int out_size, void* d_ws, size_t ws_size,
                              hipStream_t stream) {
    const float* x   = (const float*)d_in[0];   // [1,2,152,152]
    const float* rfs = (const float*)d_in[1];   // [16384,1250,1]
    const float* lw  = (const float*)d_in[2];   // [16384,625,1]
    const float* ada = (const float*)d_in[3];   // [1,1,128,128]

    float* out      = (float*)d_out;
    float* raw_aff  = out;
    float* latf     = out + S * S;
    float* corr     = out + 2 * S * S;
    float* tiles    = out + 2 * S * S + 1;
    float* ws       = (float*)d_ws;

    k_init<<<16, 256, 0, stream>>>(ws);
    k_afftiles<<<4096, 256, 0, stream>>>(x, rfs, ada, raw_aff, tiles, ws);
    k_lat<<<4096, 256, 0, stream>>>(raw_aff, ada, lw, latf, ws);
    k_corr<<<4096, 256, 0, stream>>>(latf, lw, ws);
    k_reduce<<<1, 256, 0, stream>>>(ws, corr);
}